// Round 8
// baseline (159.403 us; speedup 1.0000x reference)
//
#include <hip/hip_runtime.h>

// WalletGNN: 2-layer GCN, N=100000, E=800000, 128 -> 128 -> 64, fp32 in/out.
// R8: gathers restructured — lane-group-per-neighbor (16-lane/uint4 groups for
//     D=128, 8-lane groups for D=64), col indices prefetched 64-wide and
//     shfl-distributed, predicated weighted tails. One H-load instruction
//     covers 4 (resp. 8) neighbors; col loads amortized 64x.

typedef __attribute__((ext_vector_type(8))) short bf16x8;
typedef __attribute__((ext_vector_type(4))) float f32x4;

static __device__ __forceinline__ unsigned short f2bf(float f) {
    unsigned u = __builtin_bit_cast(unsigned, f);
    u += 0x7fffu + ((u >> 16) & 1u);
    return (unsigned short)(u >> 16);
}
static __device__ __forceinline__ float bflo(unsigned u) {
    return __builtin_bit_cast(float, u << 16);
}
static __device__ __forceinline__ float bfraw(unsigned u) {  // hi bf16 + junk mantissa
    return __builtin_bit_cast(float, u);
}

#define CHUNK 4096              // edges per partition block
#define NBUCKP 512              // padded bucket count (dst>>8 < 391)

// ---------- A1: per-block bucket histogram (+fused W^T bf16 prep) ----------
__global__ __launch_bounds__(256) void k_hist(const int* __restrict__ dst,
        int* __restrict__ ghist, int E, int nblk,
        const float* __restrict__ W1, const float* __restrict__ W2,
        unsigned short* __restrict__ W1t, unsigned short* __restrict__ W2t) {
    __shared__ int h[NBUCKP];
    const int tid = threadIdx.x, b = blockIdx.x;
    if (b >= nblk) {            // prep_w blocks
        int i = (b - nblk) * 256 + tid;
        if (i < 128 * 128) {
            int n = i >> 7, k = i & 127;
            W1t[i] = f2bf(W1[k * 128 + n]);
        }
        int j = i - 128 * 128;
        if (j >= 0 && j < 64 * 128) {
            int n = j >> 7, k = j & 127;
            W2t[j] = f2bf(W2[k * 64 + n]);
        }
        return;
    }
    h[tid] = 0; h[tid + 256] = 0;
    __syncthreads();
    const int base = b * CHUNK;
#pragma unroll
    for (int i = 0; i < CHUNK / 256; ++i) {
        int e = base + i * 256 + tid;
        if (e < E) atomicAdd(&h[dst[e] >> 8], 1);
    }
    __syncthreads();
    ghist[tid * nblk + b] = h[tid];
    ghist[(tid + 256) * nblk + b] = h[tid + 256];
}

// ---------- hierarchical scan helpers ----------
__global__ __launch_bounds__(256) void k_part(const int* __restrict__ v,
                                              int* __restrict__ part, int L) {
    __shared__ int s[256];
    int tid = threadIdx.x;
    int i = blockIdx.x * 256 + tid;
    s[tid] = (i < L) ? v[i] : 0;
    __syncthreads();
    for (int o = 128; o > 0; o >>= 1) {
        if (tid < o) s[tid] += s[tid + o];
        __syncthreads();
    }
    if (tid == 0) part[blockIdx.x] = s[0];
}

__global__ __launch_bounds__(512) void k_scanpart(int* __restrict__ part, int nb) {
    __shared__ int s[512];
    int tid = threadIdx.x;
    int v = (tid < nb) ? part[tid] : 0;
    s[tid] = v;
    __syncthreads();
    for (int off = 1; off < 512; off <<= 1) {
        int t = (tid >= off) ? s[tid - off] : 0;
        __syncthreads();
        s[tid] += t;
        __syncthreads();
    }
    if (tid < nb) part[tid] = s[tid] - v;   // exclusive
}

__global__ __launch_bounds__(256) void k_scan_apply(int* __restrict__ v,
        const int* __restrict__ part, int L) {
    __shared__ int s[256];
    int tid = threadIdx.x;
    int i = blockIdx.x * 256 + tid;
    int x = (i < L) ? v[i] : 0;
    s[tid] = x;
    __syncthreads();
    for (int off = 1; off < 256; off <<= 1) {
        int t = (tid >= off) ? s[tid - off] : 0;
        __syncthreads();
        s[tid] += t;
        __syncthreads();
    }
    if (i < L) v[i] = part[blockIdx.x] + s[tid] - x;
}

// ---------- A3: partition scatter via LDS cursors (packed uint32) ----------
__global__ __launch_bounds__(256) void k_scatter_part(const int* __restrict__ src,
        const int* __restrict__ dst, const int* __restrict__ S,
        unsigned* __restrict__ eb, int E, int nblk) {
    __shared__ int cur[NBUCKP];
    const int tid = threadIdx.x, b = blockIdx.x;
    cur[tid] = S[tid * nblk + b];
    cur[tid + 256] = S[(tid + 256) * nblk + b];
    __syncthreads();
    const int base = b * CHUNK;
#pragma unroll
    for (int i = 0; i < CHUNK / 256; ++i) {
        int e = base + i * 256 + tid;
        if (e < E) {
            int s = src[e], d = dst[e];
            int pos = atomicAdd(&cur[d >> 8], 1);
            eb[pos] = ((unsigned)(d & 255) << 24) | (unsigned)s;
        }
    }
}

// ---------- B: per-bucket CSR finalize (256 dst values per block) ----------
__global__ __launch_bounds__(256) void k_bucket_csr(const unsigned* __restrict__ eb,
        const int* __restrict__ S, int* __restrict__ row_ptr,
        float* __restrict__ dinv, int* __restrict__ col, int E, int nblk, int N) {
    __shared__ int h[256], sc[256], cur[256];
    const int tid = threadIdx.x, k = blockIdx.x;
    const int bstart = S[k * nblk];
    const int bend   = S[(k + 1) * nblk];
    h[tid] = 0;
    __syncthreads();
    for (int e = bstart + tid; e < bend; e += 256)
        atomicAdd(&h[eb[e] >> 24], 1);
    __syncthreads();
    int v = h[tid];
    sc[tid] = v;
    __syncthreads();
    for (int off = 1; off < 256; off <<= 1) {
        int t = (tid >= off) ? sc[tid - off] : 0;
        __syncthreads();
        sc[tid] += t;
        __syncthreads();
    }
    int excl = sc[tid] - v;
    int n = k * 256 + tid;
    if (n < N) {
        row_ptr[n] = bstart + excl;
        dinv[n] = rsqrtf((float)v + 1.0f);    // +1 self-loop
        if (n == N - 1) row_ptr[N] = bstart + excl + v;
    }
    cur[tid] = excl;
    __syncthreads();
    for (int e = bstart + tid; e < bend; e += 256) {
        unsigned ed = eb[e];
        int pos = bstart + atomicAdd(&cur[ed >> 24], 1);
        col[pos] = (int)(ed & 0xFFFFFFu);
    }
}

// ---------- MFMA GEMM: C[r][:] = bf16( dinv[r] * (A[r][:] @ B) ), K=128 ----------
template<int NC, bool ABF16>
__global__ __launch_bounds__(256) void k_gemm(const void* __restrict__ Av,
        const unsigned short* __restrict__ Wt, const float* __restrict__ dinv,
        unsigned short* __restrict__ C, int M) {
    __shared__ unsigned short sA[64][136];
    __shared__ unsigned short sW[NC][136];
    const int tid  = threadIdx.x;
    const int lane = tid & 63;
    const int wave = tid >> 6;
    const int row0 = blockIdx.x * 64;

    if (ABF16) {
        const uint4* A = (const uint4*)Av;
#pragma unroll
        for (int p = 0; p < 4; ++p) {
            int c = tid + p * 256;
            int row = c >> 4, cc = c & 15;
            uint4 v = make_uint4(0u, 0u, 0u, 0u);
            if (row0 + row < M) v = A[(size_t)(row0 + row) * 16 + cc];
            *(uint4*)&sA[row][cc * 8] = v;
        }
    } else {
        const float* A = (const float*)Av;
#pragma unroll
        for (int p = 0; p < 8; ++p) {
            int c = tid + p * 256;
            int row = c >> 5, c4 = (c & 31) * 4;
            float4 v = make_float4(0.f, 0.f, 0.f, 0.f);
            if (row0 + row < M) v = *(const float4*)&A[(size_t)(row0 + row) * 128 + c4];
            ushort4 o;
            o.x = f2bf(v.x); o.y = f2bf(v.y); o.z = f2bf(v.z); o.w = f2bf(v.w);
            *(ushort4*)&sA[row][c4] = o;
        }
    }
    {
        const uint4* W4 = (const uint4*)Wt;
#pragma unroll
        for (int p = 0; p < NC / 16; ++p) {
            int c = tid + p * 256;
            int n = c >> 4, cc = c & 15;
            *(uint4*)&sW[n][cc * 8] = W4[c];
        }
    }
    __syncthreads();

    constexpr int CT = NC / 64;
    const int colbase = wave * (NC / 4);
    const int frow = lane & 15;
    const int fk   = (lane >> 4) * 8;

    f32x4 acc[4][CT];
#pragma unroll
    for (int rt = 0; rt < 4; ++rt)
#pragma unroll
        for (int ct = 0; ct < CT; ++ct) acc[rt][ct] = (f32x4){0.f, 0.f, 0.f, 0.f};

#pragma unroll
    for (int kk = 0; kk < 128; kk += 32) {
        bf16x8 a[4], b[CT];
#pragma unroll
        for (int rt = 0; rt < 4; ++rt)
            a[rt] = *(const bf16x8*)&sA[rt * 16 + frow][kk + fk];
#pragma unroll
        for (int ct = 0; ct < CT; ++ct)
            b[ct] = *(const bf16x8*)&sW[colbase + ct * 16 + frow][kk + fk];
#pragma unroll
        for (int rt = 0; rt < 4; ++rt)
#pragma unroll
            for (int ct = 0; ct < CT; ++ct)
                acc[rt][ct] = __builtin_amdgcn_mfma_f32_16x16x32_bf16(
                    a[rt], b[ct], acc[rt][ct], 0, 0, 0);
    }

    const int crow = (lane >> 4) * 4;
#pragma unroll
    for (int rt = 0; rt < 4; ++rt) {
        int grow = row0 + rt * 16 + crow;
#pragma unroll
        for (int r = 0; r < 4; ++r) {
            if (grow + r < M) {
                float s = dinv[grow + r];
#pragma unroll
                for (int ct = 0; ct < CT; ++ct) {
                    int gcol = colbase + ct * 16 + (lane & 15);
                    C[(size_t)(grow + r) * NC + gcol] = f2bf(acc[rt][ct][r] * s);
                }
            }
        }
    }
}

// ---------- gather D=128: wave/node, 4 groups x 16 lanes, uint4/lane ----------
// Group g handles neighbor t = it+g each step; lane loads 16B of the row.
// cnt includes virtual self at t=0. col prefetched 64-wide, shfl-distributed.
template<bool ELU>
__global__ __launch_bounds__(256) void k_gather128(const unsigned* __restrict__ H,
        const int* __restrict__ row_ptr, const int* __restrict__ col,
        const float* __restrict__ dinv, const float* __restrict__ bias,
        unsigned* __restrict__ outbf, int N) {
    const int wave = threadIdx.x >> 6, lane = threadIdx.x & 63;
    const int n = blockIdx.x * 4 + wave;
    if (n >= N) return;
    const int beg = row_ptr[n];
    const int cnt = row_ptr[n + 1] - beg + 1;   // +1 virtual self at t=0
    const int g   = lane >> 4;                  // group 0..3
    const int c16 = lane & 15;                  // 16B chunk in row
    f32x4 accA = (f32x4){0.f, 0.f, 0.f, 0.f};
    f32x4 accB = (f32x4){0.f, 0.f, 0.f, 0.f};

    for (int chunk = 0; chunk < cnt; chunk += 64) {
        int t = chunk + lane;
        int cidx = n;
        if (t > 0 && t < cnt) cidx = col[beg + t - 1];
        int m = cnt - chunk; if (m > 64) m = 64;
        for (int it = 0; it < m; it += 8) {     // 2 steps -> 8 rows in flight
            int t0 = it + g, t1 = it + 4 + g;
            int ca = __shfl(cidx, t0);
            int cb = __shfl(cidx, t1);
            float wa = (t0 < m) ? 1.f : 0.f;
            float wb = (t1 < m) ? 1.f : 0.f;
            uint4 va = *(const uint4*)&H[(size_t)ca * 64 + (c16 << 2)];
            uint4 vb = *(const uint4*)&H[(size_t)cb * 64 + (c16 << 2)];
            f32x4 qa, qb;
            qa[0] = bflo(va.x); qa[1] = bfraw(va.x);
            qa[2] = bflo(va.y); qa[3] = bfraw(va.y);
            qb[0] = bflo(va.z); qb[1] = bfraw(va.z);
            qb[2] = bflo(va.w); qb[3] = bfraw(va.w);
            accA += qa * wa; accB += qb * wa;
            qa[0] = bflo(vb.x); qa[1] = bfraw(vb.x);
            qa[2] = bflo(vb.y); qa[3] = bfraw(vb.y);
            qb[0] = bflo(vb.z); qb[1] = bfraw(vb.z);
            qb[2] = bflo(vb.w); qb[3] = bfraw(vb.w);
            accA += qa * wb; accB += qb * wb;
        }
    }

#pragma unroll
    for (int k2 = 0; k2 < 4; ++k2) {            // reduce across 4 groups
        accA[k2] += __shfl_xor(accA[k2], 16);
        accB[k2] += __shfl_xor(accB[k2], 16);
        accA[k2] += __shfl_xor(accA[k2], 32);
        accB[k2] += __shfl_xor(accB[k2], 32);
    }
    if (g == 0) {                               // lanes 0..15 write the row
        float sc = dinv[n];
        float4 b0 = *(const float4*)&bias[c16 * 8];
        float4 b1 = *(const float4*)&bias[c16 * 8 + 4];
        float o0 = fmaf(accA[0], sc, b0.x), o1 = fmaf(accA[1], sc, b0.y);
        float o2 = fmaf(accA[2], sc, b0.z), o3 = fmaf(accA[3], sc, b0.w);
        float o4 = fmaf(accB[0], sc, b1.x), o5 = fmaf(accB[1], sc, b1.y);
        float o6 = fmaf(accB[2], sc, b1.z), o7 = fmaf(accB[3], sc, b1.w);
        if (ELU) {
            o0 = o0 > 0.f ? o0 : expm1f(o0);
            o1 = o1 > 0.f ? o1 : expm1f(o1);
            o2 = o2 > 0.f ? o2 : expm1f(o2);
            o3 = o3 > 0.f ? o3 : expm1f(o3);
            o4 = o4 > 0.f ? o4 : expm1f(o4);
            o5 = o5 > 0.f ? o5 : expm1f(o5);
            o6 = o6 > 0.f ? o6 : expm1f(o6);
            o7 = o7 > 0.f ? o7 : expm1f(o7);
        }
        uint4 o;
        o.x = (unsigned)f2bf(o0) | ((unsigned)f2bf(o1) << 16);
        o.y = (unsigned)f2bf(o2) | ((unsigned)f2bf(o3) << 16);
        o.z = (unsigned)f2bf(o4) | ((unsigned)f2bf(o5) << 16);
        o.w = (unsigned)f2bf(o6) | ((unsigned)f2bf(o7) << 16);
        *(uint4*)&outbf[(size_t)n * 64 + (c16 << 2)] = o;
    }
}

// ---------- gather D=64: wave/node, 8 groups x 8 lanes, uint4/lane ----------
__global__ __launch_bounds__(256) void k_gather64(const unsigned* __restrict__ H,
        const int* __restrict__ row_ptr, const int* __restrict__ col,
        const float* __restrict__ dinv, const float* __restrict__ bias,
        float* __restrict__ out, int N) {
    const int wave = threadIdx.x >> 6, lane = threadIdx.x & 63;
    const int n = blockIdx.x * 4 + wave;
    if (n >= N) return;
    const int beg = row_ptr[n];
    const int cnt = row_ptr[n + 1] - beg + 1;   // +1 virtual self at t=0
    const int g  = lane >> 3;                   // group 0..7
    const int c8 = lane & 7;                    // 16B chunk in row
    f32x4 accA = (f32x4){0.f, 0.f, 0.f, 0.f};
    f32x4 accB = (f32x4){0.f, 0.f, 0.f, 0.f};

    for (int chunk = 0; chunk < cnt; chunk += 64) {
        int t = chunk + lane;
        int cidx = n;
        if (t > 0 && t < cnt) cidx = col[beg + t - 1];
        int m = cnt - chunk; if (m > 64) m = 64;
        for (int it = 0; it < m; it += 16) {    // 2 steps -> 16 rows in flight
            int t0 = it + g, t1 = it + 8 + g;
            int ca = __shfl(cidx, t0);
            int cb = __shfl(cidx, t1);
            float wa = (t0 < m) ? 1.f : 0.f;
            float wb = (t1 < m) ? 1.f : 0.f;
            uint4 va = *(const uint4*)&H[(size_t)ca * 32 + (c8 << 2)];
            uint4 vb = *(const uint4*)&H[(size_t)cb * 32 + (c8 << 2)];
            f32x4 qa, qb;
            qa[0] = bflo(va.x); qa[1] = bfraw(va.x);
            qa[2] = bflo(va.y); qa[3] = bfraw(va.y);
            qb[0] = bflo(va.z); qb[1] = bfraw(va.z);
            qb[2] = bflo(va.w); qb[3] = bfraw(va.w);
            accA += qa * wa; accB += qb * wa;
            qa[0] = bflo(vb.x); qa[1] = bfraw(vb.x);
            qa[2] = bflo(vb.y); qa[3] = bfraw(vb.y);
            qb[0] = bflo(vb.z); qb[1] = bfraw(vb.z);
            qb[2] = bflo(vb.w); qb[3] = bfraw(vb.w);
            accA += qa * wb; accB += qb * wb;
        }
    }

#pragma unroll
    for (int k2 = 0; k2 < 4; ++k2) {            // reduce across 8 groups
        accA[k2] += __shfl_xor(accA[k2], 8);
        accB[k2] += __shfl_xor(accB[k2], 8);
        accA[k2] += __shfl_xor(accA[k2], 16);
        accB[k2] += __shfl_xor(accB[k2], 16);
        accA[k2] += __shfl_xor(accA[k2], 32);
        accB[k2] += __shfl_xor(accB[k2], 32);
    }
    if (g == 0) {                               // lanes 0..7 write the row
        float sc = dinv[n];
        float4 b0 = *(const float4*)&bias[c8 * 8];
        float4 b1 = *(const float4*)&bias[c8 * 8 + 4];
        float4 oa, ob;
        oa.x = fmaf(accA[0], sc, b0.x); oa.y = fmaf(accA[1], sc, b0.y);
        oa.z = fmaf(accA[2], sc, b0.z); oa.w = fmaf(accA[3], sc, b0.w);
        ob.x = fmaf(accB[0], sc, b1.x); ob.y = fmaf(accB[1], sc, b1.y);
        ob.z = fmaf(accB[2], sc, b1.z); ob.w = fmaf(accB[3], sc, b1.w);
        *(float4*)&out[(size_t)n * 64 + c8 * 8]     = oa;
        *(float4*)&out[(size_t)n * 64 + c8 * 8 + 4] = ob;
    }
}

extern "C" void kernel_launch(void* const* d_in, const int* in_sizes, int n_in,
                              void* d_out, int out_size, void* d_ws, size_t ws_size,
                              hipStream_t stream) {
    const float* x  = (const float*)d_in[0];
    const int*   ei = (const int*)d_in[1];
    const float* W1 = (const float*)d_in[2];
    const float* b1 = (const float*)d_in[3];
    const float* W2 = (const float*)d_in[4];
    const float* b2 = (const float*)d_in[5];
    float* out = (float*)d_out;

    const int N = in_sizes[0] / 128;   // 100000
    const int E = in_sizes[1] / 2;     // 800000
    const int* src = ei;
    const int* dst = ei + E;
    const int NPAD = (N + 63) & ~63;

    const int NBLK_A = (E + CHUNK - 1) / CHUNK;        // 196
    const int L      = NBUCKP * NBLK_A;                // 100352
    const int NBLK_S = (L + 255) / 256;                // 392  (<=512)
    const int NBUCK  = (N + 255) / 256;                // 391

    // workspace layout (4-byte units)
    unsigned off = 0;
    int* row_ptr    = (int*)d_ws + off;            off += NPAD + 64;
    float* dinv     = (float*)((int*)d_ws + off);  off += NPAD + 64;
    int* ghist      = (int*)d_ws + off;            off += (unsigned)((L + 63) & ~63);
    int* part       = (int*)d_ws + off;            off += 512;
    unsigned* eb    = (unsigned*)((int*)d_ws + off); off += (unsigned)((E + 63) & ~63);
    int* col        = (int*)d_ws + off;            off += (unsigned)((E + 63) & ~63);
    unsigned short* W1t = (unsigned short*)((int*)d_ws + off); off += 8192;
    unsigned short* W2t = (unsigned short*)((int*)d_ws + off); off += 4096;
    unsigned* H     = (unsigned*)((int*)d_ws + off); off += (unsigned)N * 64 + 64;
    unsigned* act   = (unsigned*)((int*)d_ws + off);

    // CSR build (no global atomics) + fused W prep
    k_hist<<<NBLK_A + 96, 256, 0, stream>>>(dst, ghist, E, NBLK_A, W1, W2, W1t, W2t);
    k_part<<<NBLK_S, 256, 0, stream>>>(ghist, part, L);
    k_scanpart<<<1, 512, 0, stream>>>(part, NBLK_S);
    k_scan_apply<<<NBLK_S, 256, 0, stream>>>(ghist, part, L);
    k_scatter_part<<<NBLK_A, 256, 0, stream>>>(src, dst, ghist, eb, E, NBLK_A);
    k_bucket_csr<<<NBUCK, 256, 0, stream>>>(eb, ghist, row_ptr, dinv, col, E, NBLK_A, N);

    // Layer 1
    k_gemm<128, false><<<(N + 63) / 64, 256, 0, stream>>>(x, W1t, dinv,
                                                          (unsigned short*)H, N);
    k_gather128<true><<<(N + 3) / 4, 256, 0, stream>>>(H, row_ptr, col, dinv, b1, act, N);

    // Layer 2
    k_gemm<64, true><<<(N + 63) / 64, 256, 0, stream>>>(act, W2t, dinv,
                                                        (unsigned short*)H, N);
    k_gather64<<<(N + 3) / 4, 256, 0, stream>>>(H, row_ptr, col, dinv, b2, out, N);
}

// Round 9
// 152.916 us; speedup vs baseline: 1.0424x; 1.0424x over previous
//
#include <hip/hip_runtime.h>

// WalletGNN: 2-layer GCN, N=100000, E=800000, 128 -> 128 -> 64, fp32 in/out.
// R9: R7 gather structure restored (R8's lane-group scheme regressed: added
//     VALU). Changes vs R7: (1) 32-bit H addressing (SGPR base + u32 voffset,
//     kills 64-bit mul per neighbor), (2) col indices software-pipelined
//     (next iter's cols issued before current iter's H loads).

typedef __attribute__((ext_vector_type(8))) short bf16x8;
typedef __attribute__((ext_vector_type(4))) float f32x4;

static __device__ __forceinline__ unsigned short f2bf(float f) {
    unsigned u = __builtin_bit_cast(unsigned, f);
    u += 0x7fffu + ((u >> 16) & 1u);
    return (unsigned short)(u >> 16);
}
static __device__ __forceinline__ float bflo(unsigned u) {
    return __builtin_bit_cast(float, u << 16);
}
// {lo(x), hi(x)+junk, lo(y), hi(y)+junk} — junk mantissa < 2^-8 relative.
static __device__ __forceinline__ f32x4 bfquad(uint2 v) {
    f32x4 r;
    r[0] = bflo(v.x); r[1] = __builtin_bit_cast(float, v.x);
    r[2] = bflo(v.y); r[3] = __builtin_bit_cast(float, v.y);
    return r;
}

#define CHUNK 4096              // edges per partition block
#define NBUCKP 512              // padded bucket count (dst>>8 < 391)

// ---------- A1: per-block bucket histogram (+fused W^T bf16 prep) ----------
__global__ __launch_bounds__(256) void k_hist(const int* __restrict__ dst,
        int* __restrict__ ghist, int E, int nblk,
        const float* __restrict__ W1, const float* __restrict__ W2,
        unsigned short* __restrict__ W1t, unsigned short* __restrict__ W2t) {
    __shared__ int h[NBUCKP];
    const int tid = threadIdx.x, b = blockIdx.x;
    if (b >= nblk) {            // prep_w blocks
        int i = (b - nblk) * 256 + tid;
        if (i < 128 * 128) {
            int n = i >> 7, k = i & 127;
            W1t[i] = f2bf(W1[k * 128 + n]);
        }
        int j = i - 128 * 128;
        if (j >= 0 && j < 64 * 128) {
            int n = j >> 7, k = j & 127;
            W2t[j] = f2bf(W2[k * 64 + n]);
        }
        return;
    }
    h[tid] = 0; h[tid + 256] = 0;
    __syncthreads();
    const int base = b * CHUNK;
#pragma unroll
    for (int i = 0; i < CHUNK / 256; ++i) {
        int e = base + i * 256 + tid;
        if (e < E) atomicAdd(&h[dst[e] >> 8], 1);
    }
    __syncthreads();
    ghist[tid * nblk + b] = h[tid];
    ghist[(tid + 256) * nblk + b] = h[tid + 256];
}

// ---------- hierarchical scan helpers ----------
__global__ __launch_bounds__(256) void k_part(const int* __restrict__ v,
                                              int* __restrict__ part, int L) {
    __shared__ int s[256];
    int tid = threadIdx.x;
    int i = blockIdx.x * 256 + tid;
    s[tid] = (i < L) ? v[i] : 0;
    __syncthreads();
    for (int o = 128; o > 0; o >>= 1) {
        if (tid < o) s[tid] += s[tid + o];
        __syncthreads();
    }
    if (tid == 0) part[blockIdx.x] = s[0];
}

__global__ __launch_bounds__(512) void k_scanpart(int* __restrict__ part, int nb) {
    __shared__ int s[512];
    int tid = threadIdx.x;
    int v = (tid < nb) ? part[tid] : 0;
    s[tid] = v;
    __syncthreads();
    for (int off = 1; off < 512; off <<= 1) {
        int t = (tid >= off) ? s[tid - off] : 0;
        __syncthreads();
        s[tid] += t;
        __syncthreads();
    }
    if (tid < nb) part[tid] = s[tid] - v;   // exclusive
}

__global__ __launch_bounds__(256) void k_scan_apply(int* __restrict__ v,
        const int* __restrict__ part, int L) {
    __shared__ int s[256];
    int tid = threadIdx.x;
    int i = blockIdx.x * 256 + tid;
    int x = (i < L) ? v[i] : 0;
    s[tid] = x;
    __syncthreads();
    for (int off = 1; off < 256; off <<= 1) {
        int t = (tid >= off) ? s[tid - off] : 0;
        __syncthreads();
        s[tid] += t;
        __syncthreads();
    }
    if (i < L) v[i] = part[blockIdx.x] + s[tid] - x;
}

// ---------- A3: partition scatter via LDS cursors (packed uint32) ----------
__global__ __launch_bounds__(256) void k_scatter_part(const int* __restrict__ src,
        const int* __restrict__ dst, const int* __restrict__ S,
        unsigned* __restrict__ eb, int E, int nblk) {
    __shared__ int cur[NBUCKP];
    const int tid = threadIdx.x, b = blockIdx.x;
    cur[tid] = S[tid * nblk + b];
    cur[tid + 256] = S[(tid + 256) * nblk + b];
    __syncthreads();
    const int base = b * CHUNK;
#pragma unroll
    for (int i = 0; i < CHUNK / 256; ++i) {
        int e = base + i * 256 + tid;
        if (e < E) {
            int s = src[e], d = dst[e];
            int pos = atomicAdd(&cur[d >> 8], 1);
            eb[pos] = ((unsigned)(d & 255) << 24) | (unsigned)s;
        }
    }
}

// ---------- B: per-bucket CSR finalize (256 dst values per block) ----------
__global__ __launch_bounds__(256) void k_bucket_csr(const unsigned* __restrict__ eb,
        const int* __restrict__ S, int* __restrict__ row_ptr,
        float* __restrict__ dinv, int* __restrict__ col, int E, int nblk, int N) {
    __shared__ int h[256], sc[256], cur[256];
    const int tid = threadIdx.x, k = blockIdx.x;
    const int bstart = S[k * nblk];
    const int bend   = S[(k + 1) * nblk];
    h[tid] = 0;
    __syncthreads();
    for (int e = bstart + tid; e < bend; e += 256)
        atomicAdd(&h[eb[e] >> 24], 1);
    __syncthreads();
    int v = h[tid];
    sc[tid] = v;
    __syncthreads();
    for (int off = 1; off < 256; off <<= 1) {
        int t = (tid >= off) ? sc[tid - off] : 0;
        __syncthreads();
        sc[tid] += t;
        __syncthreads();
    }
    int excl = sc[tid] - v;
    int n = k * 256 + tid;
    if (n < N) {
        row_ptr[n] = bstart + excl;
        dinv[n] = rsqrtf((float)v + 1.0f);    // +1 self-loop
        if (n == N - 1) row_ptr[N] = bstart + excl + v;
    }
    cur[tid] = excl;
    __syncthreads();
    for (int e = bstart + tid; e < bend; e += 256) {
        unsigned ed = eb[e];
        int pos = bstart + atomicAdd(&cur[ed >> 24], 1);
        col[pos] = (int)(ed & 0xFFFFFFu);
    }
}

// ---------- MFMA GEMM: C[r][:] = bf16( dinv[r] * (A[r][:] @ B) ), K=128 ----------
template<int NC, bool ABF16>
__global__ __launch_bounds__(256) void k_gemm(const void* __restrict__ Av,
        const unsigned short* __restrict__ Wt, const float* __restrict__ dinv,
        unsigned short* __restrict__ C, int M) {
    __shared__ unsigned short sA[64][136];
    __shared__ unsigned short sW[NC][136];
    const int tid  = threadIdx.x;
    const int lane = tid & 63;
    const int wave = tid >> 6;
    const int row0 = blockIdx.x * 64;

    if (ABF16) {
        const uint4* A = (const uint4*)Av;
#pragma unroll
        for (int p = 0; p < 4; ++p) {
            int c = tid + p * 256;
            int row = c >> 4, cc = c & 15;
            uint4 v = make_uint4(0u, 0u, 0u, 0u);
            if (row0 + row < M) v = A[(size_t)(row0 + row) * 16 + cc];
            *(uint4*)&sA[row][cc * 8] = v;
        }
    } else {
        const float* A = (const float*)Av;
#pragma unroll
        for (int p = 0; p < 8; ++p) {
            int c = tid + p * 256;
            int row = c >> 5, c4 = (c & 31) * 4;
            float4 v = make_float4(0.f, 0.f, 0.f, 0.f);
            if (row0 + row < M) v = *(const float4*)&A[(size_t)(row0 + row) * 128 + c4];
            ushort4 o;
            o.x = f2bf(v.x); o.y = f2bf(v.y); o.z = f2bf(v.z); o.w = f2bf(v.w);
            *(ushort4*)&sA[row][c4] = o;
        }
    }
    {
        const uint4* W4 = (const uint4*)Wt;
#pragma unroll
        for (int p = 0; p < NC / 16; ++p) {
            int c = tid + p * 256;
            int n = c >> 4, cc = c & 15;
            *(uint4*)&sW[n][cc * 8] = W4[c];
        }
    }
    __syncthreads();

    constexpr int CT = NC / 64;
    const int colbase = wave * (NC / 4);
    const int frow = lane & 15;
    const int fk   = (lane >> 4) * 8;

    f32x4 acc[4][CT];
#pragma unroll
    for (int rt = 0; rt < 4; ++rt)
#pragma unroll
        for (int ct = 0; ct < CT; ++ct) acc[rt][ct] = (f32x4){0.f, 0.f, 0.f, 0.f};

#pragma unroll
    for (int kk = 0; kk < 128; kk += 32) {
        bf16x8 a[4], b[CT];
#pragma unroll
        for (int rt = 0; rt < 4; ++rt)
            a[rt] = *(const bf16x8*)&sA[rt * 16 + frow][kk + fk];
#pragma unroll
        for (int ct = 0; ct < CT; ++ct)
            b[ct] = *(const bf16x8*)&sW[colbase + ct * 16 + frow][kk + fk];
#pragma unroll
        for (int rt = 0; rt < 4; ++rt)
#pragma unroll
            for (int ct = 0; ct < CT; ++ct)
                acc[rt][ct] = __builtin_amdgcn_mfma_f32_16x16x32_bf16(
                    a[rt], b[ct], acc[rt][ct], 0, 0, 0);
    }

    const int crow = (lane >> 4) * 4;
#pragma unroll
    for (int rt = 0; rt < 4; ++rt) {
        int grow = row0 + rt * 16 + crow;
#pragma unroll
        for (int r = 0; r < 4; ++r) {
            if (grow + r < M) {
                float s = dinv[grow + r];
#pragma unroll
                for (int ct = 0; ct < CT; ++ct) {
                    int gcol = colbase + ct * 16 + (lane & 15);
                    C[(size_t)(grow + r) * NC + gcol] = f2bf(acc[rt][ct][r] * s);
                }
            }
        }
    }
}

// ---------- gather D=128: wave/node, half-wave slices, col-pipelined ----------
template<bool ELU>
__global__ __launch_bounds__(256) void k_gather128(const unsigned* __restrict__ H,
        const int* __restrict__ row_ptr, const int* __restrict__ col,
        const float* __restrict__ dinv, const float* __restrict__ bias,
        unsigned* __restrict__ outbf, int N) {
    const int wave = threadIdx.x >> 6, lane = threadIdx.x & 63;
    const int n = blockIdx.x * 4 + wave;
    if (n >= N) return;
    const int beg = row_ptr[n], end = row_ptr[n + 1];
    const int half = lane >> 5;
    const unsigned s2 = (unsigned)(lane & 31) * 2u;   // uint-index in row
    f32x4 acc = (f32x4){0.f, 0.f, 0.f, 0.f};

    if (half == 0) {                            // self row
        uint2 v = *(const uint2*)&H[((unsigned)n << 6) + s2];
        acc += bfquad(v);
    }
    int j = beg + half;
    // 4-deep main loop with next-iteration col prefetch
    int c0, c1, c2, c3;
    bool have = (j + 6 < end);
    if (have) { c0 = col[j]; c1 = col[j + 2]; c2 = col[j + 4]; c3 = col[j + 6]; }
    while (have) {
        int jn = j + 8;
        bool haven = (jn + 6 < end);
        int d0 = c0, d1 = c0, d2 = c0, d3 = c0;
        if (haven) { d0 = col[jn]; d1 = col[jn + 2]; d2 = col[jn + 4]; d3 = col[jn + 6]; }
        uint2 v0 = *(const uint2*)&H[((unsigned)c0 << 6) + s2];
        uint2 v1 = *(const uint2*)&H[((unsigned)c1 << 6) + s2];
        uint2 v2 = *(const uint2*)&H[((unsigned)c2 << 6) + s2];
        uint2 v3 = *(const uint2*)&H[((unsigned)c3 << 6) + s2];
        acc += bfquad(v0);
        acc += bfquad(v1);
        acc += bfquad(v2);
        acc += bfquad(v3);
        j = jn; c0 = d0; c1 = d1; c2 = d2; c3 = d3; have = haven;
    }
    if (j < end) {                              // predicated tail (<=3 items)
        const int e1 = end - 1;
        int j1 = j + 2, j2 = j + 4;
        int t0 = col[j];
        int t1 = col[j1 <= e1 ? j1 : e1];       // clamped: cache-hot row
        int t2 = col[j2 <= e1 ? j2 : e1];
        float w1 = (j1 < end) ? 1.f : 0.f;
        float w2 = (j2 < end) ? 1.f : 0.f;
        uint2 v0 = *(const uint2*)&H[((unsigned)t0 << 6) + s2];
        uint2 v1 = *(const uint2*)&H[((unsigned)t1 << 6) + s2];
        uint2 v2 = *(const uint2*)&H[((unsigned)t2 << 6) + s2];
        acc += bfquad(v0);
        acc += bfquad(v1) * w1;
        acc += bfquad(v2) * w2;
    }

    float a0 = acc[0], a1 = acc[1], a2 = acc[2], a3 = acc[3];
    a0 += __shfl_xor(a0, 32); a1 += __shfl_xor(a1, 32);
    a2 += __shfl_xor(a2, 32); a3 += __shfl_xor(a3, 32);
    if (half == 0) {
        float sc = dinv[n];
        float4 b = *(const float4*)&bias[2 * s2];
        float o0 = fmaf(a0, sc, b.x), o1 = fmaf(a1, sc, b.y);
        float o2 = fmaf(a2, sc, b.z), o3 = fmaf(a3, sc, b.w);
        if (ELU) {
            o0 = o0 > 0.f ? o0 : expm1f(o0);
            o1 = o1 > 0.f ? o1 : expm1f(o1);
            o2 = o2 > 0.f ? o2 : expm1f(o2);
            o3 = o3 > 0.f ? o3 : expm1f(o3);
        }
        uint2 o;
        o.x = (unsigned)f2bf(o0) | ((unsigned)f2bf(o1) << 16);
        o.y = (unsigned)f2bf(o2) | ((unsigned)f2bf(o3) << 16);
        *(uint2*)&outbf[((unsigned)n << 6) + s2] = o;
    }
}

// ---------- gather D=64: quarter-wave slices, 4-deep, col-pipelined ----------
__global__ __launch_bounds__(256) void k_gather64(const unsigned* __restrict__ H,
        const int* __restrict__ row_ptr, const int* __restrict__ col,
        const float* __restrict__ dinv, const float* __restrict__ bias,
        float* __restrict__ out, int N) {
    const int wave = threadIdx.x >> 6, lane = threadIdx.x & 63;
    const int n = blockIdx.x * 4 + wave;
    if (n >= N) return;
    const int beg = row_ptr[n], end = row_ptr[n + 1];
    const int q = lane >> 4;
    const unsigned s2 = (unsigned)(lane & 15) * 2u;
    f32x4 acc = (f32x4){0.f, 0.f, 0.f, 0.f};

    if (q == 0) {                               // self row
        uint2 v = *(const uint2*)&H[((unsigned)n << 5) + s2];
        acc += bfquad(v);
    }
    int j = beg + q;
    int c0, c1, c2, c3;
    bool have = (j + 12 < end);
    if (have) { c0 = col[j]; c1 = col[j + 4]; c2 = col[j + 8]; c3 = col[j + 12]; }
    while (have) {
        int jn = j + 16;
        bool haven = (jn + 12 < end);
        int d0 = c0, d1 = c0, d2 = c0, d3 = c0;
        if (haven) { d0 = col[jn]; d1 = col[jn + 4]; d2 = col[jn + 8]; d3 = col[jn + 12]; }
        uint2 v0 = *(const uint2*)&H[((unsigned)c0 << 5) + s2];
        uint2 v1 = *(const uint2*)&H[((unsigned)c1 << 5) + s2];
        uint2 v2 = *(const uint2*)&H[((unsigned)c2 << 5) + s2];
        uint2 v3 = *(const uint2*)&H[((unsigned)c3 << 5) + s2];
        acc += bfquad(v0);
        acc += bfquad(v1);
        acc += bfquad(v2);
        acc += bfquad(v3);
        j = jn; c0 = d0; c1 = d1; c2 = d2; c3 = d3; have = haven;
    }
    if (j < end) {                              // predicated tail (<=3 items)
        const int e1 = end - 1;
        int j1 = j + 4, j2 = j + 8;
        int t0 = col[j];
        int t1 = col[j1 <= e1 ? j1 : e1];
        int t2 = col[j2 <= e1 ? j2 : e1];
        float w1 = (j1 < end) ? 1.f : 0.f;
        float w2 = (j2 < end) ? 1.f : 0.f;
        uint2 v0 = *(const uint2*)&H[((unsigned)t0 << 5) + s2];
        uint2 v1 = *(const uint2*)&H[((unsigned)t1 << 5) + s2];
        uint2 v2 = *(const uint2*)&H[((unsigned)t2 << 5) + s2];
        acc += bfquad(v0);
        acc += bfquad(v1) * w1;
        acc += bfquad(v2) * w2;
    }

    float a0 = acc[0], a1 = acc[1], a2 = acc[2], a3 = acc[3];
    a0 += __shfl_xor(a0, 16); a1 += __shfl_xor(a1, 16);
    a2 += __shfl_xor(a2, 16); a3 += __shfl_xor(a3, 16);
    a0 += __shfl_xor(a0, 32); a1 += __shfl_xor(a1, 32);
    a2 += __shfl_xor(a2, 32); a3 += __shfl_xor(a3, 32);
    if (q == 0) {
        float sc = dinv[n];
        float4 b = *(const float4*)&bias[2 * s2];
        float4 o;
        o.x = fmaf(a0, sc, b.x); o.y = fmaf(a1, sc, b.y);
        o.z = fmaf(a2, sc, b.z); o.w = fmaf(a3, sc, b.w);
        *(float4*)&out[((unsigned)n << 6) + 2 * s2] = o;
    }
}

extern "C" void kernel_launch(void* const* d_in, const int* in_sizes, int n_in,
                              void* d_out, int out_size, void* d_ws, size_t ws_size,
                              hipStream_t stream) {
    const float* x  = (const float*)d_in[0];
    const int*   ei = (const int*)d_in[1];
    const float* W1 = (const float*)d_in[2];
    const float* b1 = (const float*)d_in[3];
    const float* W2 = (const float*)d_in[4];
    const float* b2 = (const float*)d_in[5];
    float* out = (float*)d_out;

    const int N = in_sizes[0] / 128;   // 100000
    const int E = in_sizes[1] / 2;     // 800000
    const int* src = ei;
    const int* dst = ei + E;
    const int NPAD = (N + 63) & ~63;

    const int NBLK_A = (E + CHUNK - 1) / CHUNK;        // 196
    const int L      = NBUCKP * NBLK_A;                // 100352
    const int NBLK_S = (L + 255) / 256;                // 392  (<=512)
    const int NBUCK  = (N + 255) / 256;                // 391

    // workspace layout (4-byte units)
    unsigned off = 0;
    int* row_ptr    = (int*)d_ws + off;            off += NPAD + 64;
    float* dinv     = (float*)((int*)d_ws + off);  off += NPAD + 64;
    int* ghist      = (int*)d_ws + off;            off += (unsigned)((L + 63) & ~63);
    int* part       = (int*)d_ws + off;            off += 512;
    unsigned* eb    = (unsigned*)((int*)d_ws + off); off += (unsigned)((E + 63) & ~63);
    int* col        = (int*)d_ws + off;            off += (unsigned)((E + 63) & ~63);
    unsigned short* W1t = (unsigned short*)((int*)d_ws + off); off += 8192;
    unsigned short* W2t = (unsigned short*)((int*)d_ws + off); off += 4096;
    unsigned* H     = (unsigned*)((int*)d_ws + off); off += (unsigned)N * 64 + 64;
    unsigned* act   = (unsigned*)((int*)d_ws + off);

    // CSR build (no global atomics) + fused W prep
    k_hist<<<NBLK_A + 96, 256, 0, stream>>>(dst, ghist, E, NBLK_A, W1, W2, W1t, W2t);
    k_part<<<NBLK_S, 256, 0, stream>>>(ghist, part, L);
    k_scanpart<<<1, 512, 0, stream>>>(part, NBLK_S);
    k_scan_apply<<<NBLK_S, 256, 0, stream>>>(ghist, part, L);
    k_scatter_part<<<NBLK_A, 256, 0, stream>>>(src, dst, ghist, eb, E, NBLK_A);
    k_bucket_csr<<<NBUCK, 256, 0, stream>>>(eb, ghist, row_ptr, dinv, col, E, NBLK_A, N);

    // Layer 1
    k_gemm<128, false><<<(N + 63) / 64, 256, 0, stream>>>(x, W1t, dinv,
                                                          (unsigned short*)H, N);
    k_gather128<true><<<(N + 3) / 4, 256, 0, stream>>>(H, row_ptr, col, dinv, b1, act, N);

    // Layer 2
    k_gemm<64, true><<<(N + 63) / 64, 256, 0, stream>>>(act, W2t, dinv,
                                                        (unsigned short*)H, N);
    k_gather64<<<(N + 3) / 4, 256, 0, stream>>>(H, row_ptr, col, dinv, b2, out, N);
}